// Round 1
// 760.787 us; speedup vs baseline: 1.0332x; 1.0332x over previous
//
#include <hip/hip_runtime.h>
#include <math.h>

// Problem constants
constexpr int Hdim  = 128;
constexpr int Npn   = 64;
constexpr int Eg    = 2016;          // N*(N-1)/2
constexpr int Gg    = 512;
constexpr int TOT   = Gg * Eg;       // 1,032,192 edges
constexpr int ROWS  = 32;            // rows per tile
constexpr int TPB   = 16;            // tiles per block
constexpr int NBLK  = TOT / (ROWS * TPB);   // 2016 blocks
constexpr int PITCH = 136;           // LDS row pitch in bf16 elems (16B-aligned rows)

typedef unsigned short ushortx8 __attribute__((ext_vector_type(8)));
typedef __bf16         bf16x8   __attribute__((ext_vector_type(8)));
typedef float          floatx4  __attribute__((ext_vector_type(4)));

static __device__ __forceinline__ unsigned short f2bf(float f) {
    unsigned int u = __float_as_uint(f);
    u += 0x7FFFu + ((u >> 16) & 1u);   // round-to-nearest-even
    return (unsigned short)(u >> 16);
}

// pack 2 f32 -> 2 bf16 in one instruction (lo -> [15:0], hi -> [31:16])
static __device__ __forceinline__ unsigned int cvt_pk_bf16(float lo, float hi) {
    unsigned int r;
    asm("v_cvt_pk_bf16_f32 %0, %1, %2" : "=v"(r) : "v"(lo), "v"(hi));
    return r;
}

// Branch-free exact-erf GELU. Abramowitz-Stegun 7.1.26: |err_erf| <= ~1.5e-7,
// well under bf16 storage noise. rcp+exp2 are single-instruction on gfx950.
static __device__ __forceinline__ float gelu_fast(float x) {
    const float z = fabsf(x) * 0.70710678118654752440f;
    const float t = __builtin_amdgcn_rcpf(fmaf(0.3275911f, z, 1.0f));
    float p = fmaf(1.061405429f, t, -1.453152027f);
    p = fmaf(p, t,  1.421413741f);
    p = fmaf(p, t, -0.284496736f);
    p = fmaf(p, t,  0.254829592f);
    p *= t;
    const float e  = __builtin_amdgcn_exp2f(z * z * -1.4426950408889634f);
    const float er = fmaf(-p, e, 1.0f);            // erf(|x|/sqrt2)
    return 0.5f * x * (1.0f + copysignf(er, x));
}

static __device__ __forceinline__ floatx4 mfma16(ushortx8 a, ushortx8 b, floatx4 c) {
    return __builtin_amdgcn_mfma_f32_16x16x32_bf16(
        __builtin_bit_cast(bf16x8, a), __builtin_bit_cast(bf16x8, b), c, 0, 0, 0);
}

typedef __attribute__((address_space(1))) const unsigned int gu32;
typedef __attribute__((address_space(3))) unsigned int       lu32;

// async HBM -> LDS, 16B per lane; LDS dest = wave-uniform base + lane*16
static __device__ __forceinline__ void gload_lds16(const float* g, float* l) {
    __builtin_amdgcn_global_load_lds((gu32*)(const void*)g, (lu32*)(void*)l, 16, 0, 0);
}

// Kernel 1: per-edge MLP scores, scattered to out[g*Eg + idx].
// 256 threads = 4 waves; TPB tiles of 32 rows per block, async-staged raw X.
__global__ __launch_bounds__(256, 4)
void scores_kernel(const float* __restrict__ X, const int* __restrict__ ei,
                   const float* __restrict__ lng, const float* __restrict__ lnb,
                   const float* __restrict__ W1, const float* __restrict__ b1,
                   const float* __restrict__ W2, const float* __restrict__ b2,
                   const float* __restrict__ W3, const float* __restrict__ b3,
                   float* __restrict__ out)
{
    __shared__ float          raw[ROWS * Hdim];    // 16 KB fp32 staging
    __shared__ unsigned short Xl [ROWS * PITCH];   // LN'd activations, bf16
    __shared__ unsigned short H1l[ROWS * PITCH];   // gelu(X@W1'), bf16
    __shared__ float          part[4 * ROWS];      // per-wave partial dots

    const int tid  = threadIdx.x;
    const int wave = tid >> 6;
    const int lane = tid & 63;
    const int q    = lane >> 4;    // k-group / row-quad
    const int c16  = lane & 15;    // n / m within MFMA tile

    const size_t blockRow0 = (size_t)blockIdx.x * (ROWS * TPB);

    // ---- issue async fill of raw for tile 0 (overlaps weight prologue) ----
    {
        const float* src = X + blockRow0 * Hdim;
        const int fo = wave * 256 + lane * 4;
#pragma unroll
        for (int k = 0; k < 4; ++k)
            gload_lds16(src + fo + k * 1024, raw + wave * 256 + k * 1024);
    }

    // ---- Weight fragments in registers; fold LN affine into W1/b1 ----
    // (x_hat*g + b) @ W1 + b1  ==  x_hat @ (g o W1) + (b @ W1 + b1)
    ushortx8 B1f[2][4];
    float    b1v[2];
#pragma unroll
    for (int c = 0; c < 2; ++c) {
        const int n = (2 * wave + c) * 16 + c16;
        float pb = 0.f;
#pragma unroll
        for (int kt = 0; kt < 4; ++kt) {
            ushortx8 f;
#pragma unroll
            for (int j = 0; j < 8; ++j) {
                const int k = kt * 32 + q * 8 + j;
                const float w = W1[k * Hdim + n];
                pb   = fmaf(lnb[k], w, pb);
                f[j] = f2bf(lng[k] * w);
            }
            B1f[c][kt] = f;
        }
        pb += __shfl_xor(pb, 16);      // sum over q-groups (k-slices)
        pb += __shfl_xor(pb, 32);
        b1v[c] = b1[n] + pb;
    }
    const int n2 = wave * 16 + c16;
    ushortx8 B2f[4];
#pragma unroll
    for (int kt = 0; kt < 4; ++kt) {
        ushortx8 f;
#pragma unroll
        for (int j = 0; j < 8; ++j)
            f[j] = f2bf(W2[(kt * 32 + q * 8 + j) * 64 + n2]);
        B2f[kt] = f;
    }
    const float b2v = b2[n2];
    const float w3v = W3[n2];
    const float b3v = b3[0];

    const int row = tid >> 3;          // 0..31   (8 threads per row)
    const int cg  = tid & 7;           // column group: cols cg*4 + k*32

    __syncthreads();                   // raw[tile0] ready (vmcnt drained)

    for (int t = 0; t < TPB; ++t) {
        // ---- Phase A: LN from raw (LDS) -> Xl (bf16) ----
        float4 x[4];
#pragma unroll
        for (int k = 0; k < 4; ++k)
            x[k] = *reinterpret_cast<const float4*>(&raw[row * Hdim + cg * 4 + k * 32]);
        float s = 0.f, s2 = 0.f;
#pragma unroll
        for (int k = 0; k < 4; ++k) {
            s += x[k].x + x[k].y + x[k].z + x[k].w;
            s2 = fmaf(x[k].x, x[k].x, s2);
            s2 = fmaf(x[k].y, x[k].y, s2);
            s2 = fmaf(x[k].z, x[k].z, s2);
            s2 = fmaf(x[k].w, x[k].w, s2);
        }
        s  += __shfl_xor(s, 1);  s  += __shfl_xor(s, 2);  s  += __shfl_xor(s, 4);
        s2 += __shfl_xor(s2, 1); s2 += __shfl_xor(s2, 2); s2 += __shfl_xor(s2, 4);
        const float mu  = s * 0.0078125f;
        const float var = fmaf(s2, 0.0078125f, -mu * mu);
        const float rs  = rsqrtf(var + 1e-5f);
        const float nm  = -mu * rs;
#pragma unroll
        for (int k = 0; k < 4; ++k) {
            uint2 pk;
            pk.x = cvt_pk_bf16(fmaf(x[k].x, rs, nm), fmaf(x[k].y, rs, nm));
            pk.y = cvt_pk_bf16(fmaf(x[k].z, rs, nm), fmaf(x[k].w, rs, nm));
            *reinterpret_cast<uint2*>(&Xl[row * PITCH + cg * 4 + k * 32]) = pk;
        }
        __syncthreads();               // bar1: Xl ready, raw fully consumed

        // refill raw for next tile (async; drained at bar2 under GEMM1+GELU1)
        if (t + 1 < TPB) {
            const float* src = X + (blockRow0 + (size_t)(t + 1) * ROWS) * Hdim;
            const int fo = wave * 256 + lane * 4;
#pragma unroll
            for (int k = 0; k < 4; ++k)
                gload_lds16(src + fo + k * 1024, raw + wave * 256 + k * 1024);
        }
        // prefetch edge indices for this tile's scatter
        int sv = 0, dv = 0;
        const int e = (int)(blockRow0 + (size_t)t * ROWS) + tid;
        if (tid < ROWS) { sv = ei[e]; dv = ei[TOT + e]; }

        // ---- GEMM1: [32x128] @ [128x128] ----
        floatx4 acc[2][2];
#pragma unroll
        for (int rt = 0; rt < 2; ++rt)
#pragma unroll
            for (int c = 0; c < 2; ++c)
                acc[rt][c] = floatx4{0.f, 0.f, 0.f, 0.f};
#pragma unroll
        for (int kt = 0; kt < 4; ++kt) {
            ushortx8 a0 = *reinterpret_cast<const ushortx8*>(&Xl[(c16)      * PITCH + kt * 32 + q * 8]);
            ushortx8 a1 = *reinterpret_cast<const ushortx8*>(&Xl[(16 + c16) * PITCH + kt * 32 + q * 8]);
            acc[0][0] = mfma16(a0, B1f[0][kt], acc[0][0]);
            acc[0][1] = mfma16(a0, B1f[1][kt], acc[0][1]);
            acc[1][0] = mfma16(a1, B1f[0][kt], acc[1][0]);
            acc[1][1] = mfma16(a1, B1f[1][kt], acc[1][1]);
        }

        // GELU + store H1 (bf16). C layout: col=lane&15, row=q*4+r.
#pragma unroll
        for (int rt = 0; rt < 2; ++rt) {
#pragma unroll
            for (int c = 0; c < 2; ++c) {
                const float bb = b1v[c];
                const int col  = (2 * wave + c) * 16 + c16;
                const float h0 = gelu_fast(acc[rt][c][0] + bb);
                const float h1 = gelu_fast(acc[rt][c][1] + bb);
                const float h2 = gelu_fast(acc[rt][c][2] + bb);
                const float h3 = gelu_fast(acc[rt][c][3] + bb);
                const unsigned int p01 = cvt_pk_bf16(h0, h1);
                const unsigned int p23 = cvt_pk_bf16(h2, h3);
                const int rbase = rt * 16 + q * 4;
                H1l[(rbase + 0) * PITCH + col] = (unsigned short)p01;
                H1l[(rbase + 1) * PITCH + col] = (unsigned short)(p01 >> 16);
                H1l[(rbase + 2) * PITCH + col] = (unsigned short)p23;
                H1l[(rbase + 3) * PITCH + col] = (unsigned short)(p23 >> 16);
            }
        }
        __syncthreads();               // bar2: H1 ready; raw refill drained here

        // ---- GEMM2: [32x128] @ [128x64] ----
        floatx4 acc2[2];
        acc2[0] = floatx4{0.f, 0.f, 0.f, 0.f};
        acc2[1] = floatx4{0.f, 0.f, 0.f, 0.f};
#pragma unroll
        for (int kt = 0; kt < 4; ++kt) {
            ushortx8 a0 = *reinterpret_cast<const ushortx8*>(&H1l[(c16)      * PITCH + kt * 32 + q * 8]);
            ushortx8 a1 = *reinterpret_cast<const ushortx8*>(&H1l[(16 + c16) * PITCH + kt * 32 + q * 8]);
            acc2[0] = mfma16(a0, B2f[kt], acc2[0]);
            acc2[1] = mfma16(a1, B2f[kt], acc2[1]);
        }

        // ---- Epilogue: gelu, *W3, reduce 16 cols per wave ----
#pragma unroll
        for (int rt = 0; rt < 2; ++rt) {
            floatx4 pv;
#pragma unroll
            for (int r = 0; r < 4; ++r)
                pv[r] = gelu_fast(acc2[rt][r] + b2v) * w3v;
#pragma unroll
            for (int m = 1; m < 16; m <<= 1) {
#pragma unroll
                for (int r = 0; r < 4; ++r) pv[r] += __shfl_xor(pv[r], m);
            }
            if (c16 == 0)
                *reinterpret_cast<floatx4*>(&part[wave * ROWS + rt * 16 + q * 4]) = pv;
        }
        __syncthreads();               // bar3: part ready

        // ---- Scatter scores via edge_index ----
        if (tid < ROWS) {
            const float sc = b3v + part[tid] + part[ROWS + tid]
                           + part[2 * ROWS + tid] + part[3 * ROWS + tid];
            const int g  = sv >> 6;            // N = 64
            const int ls = sv & 63, ld = dv & 63;
            const int i2 = min(ls, ld), j2 = max(ls, ld);
            if (ls != ld) {
                const int idx = i2 * Npn - ((i2 * (i2 + 1)) >> 1) + (j2 - i2 - 1);
                out[g * Eg + idx] = sc;
            }
        }
        // no barrier needed: part is next written only after bar1+bar2 of t+1,
        // and raw (refilled for t+1) was drained at bar2 above.
    }
}

// Kernel 2: in-place softmax over each graph's 2016 logits. One block per graph.
__global__ __launch_bounds__(256)
void softmax_kernel(float* __restrict__ buf)
{
    __shared__ float red[4];
    const int tid  = threadIdx.x;
    const int wave = tid >> 6;
    const int lane = tid & 63;
    const int base = blockIdx.x * Eg;

    float v[8];
    float mx = -3.4e38f;
#pragma unroll
    for (int k = 0; k < 8; ++k) {
        const int idx = tid + 256 * k;
        v[k] = (idx < Eg) ? buf[base + idx] : -3.4e38f;
        mx = fmaxf(mx, v[k]);
    }
#pragma unroll
    for (int m = 1; m < 64; m <<= 1) mx = fmaxf(mx, __shfl_xor(mx, m));
    if (lane == 0) red[wave] = mx;
    __syncthreads();
    mx = fmaxf(fmaxf(red[0], red[1]), fmaxf(red[2], red[3]));
    __syncthreads();

    float sum = 0.f;
#pragma unroll
    for (int k = 0; k < 8; ++k) {
        const int idx = tid + 256 * k;
        if (idx < Eg) {
            v[k] = __builtin_amdgcn_exp2f((v[k] - mx) * 1.4426950408889634f);
            sum += v[k];
        }
    }
#pragma unroll
    for (int m = 1; m < 64; m <<= 1) sum += __shfl_xor(sum, m);
    if (lane == 0) red[wave] = sum;
    __syncthreads();
    sum = red[0] + red[1] + red[2] + red[3];
    const float inv = 1.0f / sum;

#pragma unroll
    for (int k = 0; k < 8; ++k) {
        const int idx = tid + 256 * k;
        if (idx < Eg) buf[base + idx] = v[k] * inv;
    }
}

extern "C" void kernel_launch(void* const* d_in, const int* in_sizes, int n_in,
                              void* d_out, int out_size, void* d_ws, size_t ws_size,
                              hipStream_t stream)
{
    const float* Xf  = (const float*)d_in[0];   // edge_features [TOT,128]
    const int*   ei  = (const int*)d_in[1];     // edge_index [2, TOT]
    // d_in[2] batch, d_in[3] num_nodes_per_graph: unused (structure is canonical)
    const float* lng = (const float*)d_in[4];
    const float* lnb = (const float*)d_in[5];
    const float* W1  = (const float*)d_in[6];
    const float* b1  = (const float*)d_in[7];
    const float* W2  = (const float*)d_in[8];
    const float* b2  = (const float*)d_in[9];
    const float* W3  = (const float*)d_in[10];
    const float* b3  = (const float*)d_in[11];
    float* out = (float*)d_out;

    hipLaunchKernelGGL(scores_kernel, dim3(NBLK), dim3(256), 0, stream,
                       Xf, ei, lng, lnb, W1, b1, W2, b2, W3, b3, out);
    hipLaunchKernelGGL(softmax_kernel, dim3(Gg), dim3(256), 0, stream, out);
}